// Round 3
// baseline (365.953 us; speedup 1.0000x reference)
//
#include <hip/hip_runtime.h>
#include <math.h>

#define B_ 16
#define H_ 224
#define W_ 224
#define HP_ 226
#define WP_ 226
#define CIN_ 3
#define COUT_ 64
#define NPIX_ (B_ * H_ * W_)      /* 802816 */
#define NPAD_ (B_ * HP_ * WP_)    /* 817216 */
#define NBLK_ (NPIX_ / 256)       /* 3136 */
#define MAXNORM_ 0.999f
#define MINN_ 1e-7f
#define TCL_ (1.0f - 1e-5f)
#define LCLAMP_ 3.8002012f        /* atanh(0.999) */
#define BN_EPS_ 1e-5f
#define NF_ ((float)NPIX_)
/* Half-tile LDS row stride (floats): 32 ch + 4 pad = 36 = 9 quads (odd).
   b128 write: lane start-bank = (36*lane)%32 = 4*lane%32 -> per 16-lane phase
   each 4-bank group hit exactly 2x = the hard floor. b128 read (rb):
   start-bank 4*(pr8+qi)%32 -> 8 distinct groups per 8-lane phase = floor. */
#define PADW2_ 36

typedef float v4f __attribute__((ext_vector_type(4)));

// 64 accumulators as 16 NAMED vector members. Never indexed with a variable:
// all access is macro-expanded constant member names -> first-class SSA values,
// immune to the SROA-before-unroll alloca trap that left R1/R2 at 48 VGPRs with
// 250+ MB of scratch spill traffic (WRITE_SIZE 2.5x ideal, VGPR_Count frozen).
struct Acc {
  v4f v0, v1, v2, v3, v4, v5, v6, v7, v8, v9, v10, v11, v12, v13, v14, v15;
};

#define EACH16(X) X(0) X(1) X(2) X(3) X(4) X(5) X(6) X(7) \
                  X(8) X(9) X(10) X(11) X(12) X(13) X(14) X(15)
#define EACH8LO(X) X(0) X(1) X(2) X(3) X(4) X(5) X(6) X(7)
#define EACH8HI(X) X(8) X(9) X(10) X(11) X(12) X(13) X(14) X(15)

// ---------------------------------------------------------------------------
// K0: x (NCHW f32) -> u0p (padded NHWC4): u0 = logmap0(projx(x)) per pixel,
// zero halo ring. atanh(t) = 0.5*log((1+t)/(1-t)) via v_log_f32.
// ---------------------------------------------------------------------------
__global__ void k0_transform(const float* __restrict__ x, float4* __restrict__ u0p) {
  int idx = blockIdx.x * 256 + threadIdx.x;
  if (idx >= NPAD_) return;
  int b = idx / (HP_ * WP_);
  int r = idx % (HP_ * WP_);
  int yp = r / WP_, xp = r % WP_;
  float4 o = make_float4(0.f, 0.f, 0.f, 0.f);
  if (yp >= 1 && yp <= H_ && xp >= 1 && xp <= W_) {
    const float* xb = x + (size_t)b * (CIN_ * H_ * W_) + (size_t)(yp - 1) * W_ + (xp - 1);
    float v0 = xb[0];
    float v1 = xb[H_ * W_];
    float v2 = xb[2 * H_ * W_];
    // projx
    float n = sqrtf(fmaf(v0, v0, fmaf(v1, v1, v2 * v2)));
    float ncl = fmaxf(n, MINN_);
    float s = fminf(1.0f, MAXNORM_ / ncl);
    float p0 = v0 * s, p1 = v1 * s, p2 = v2 * s;
    // logmap0
    float np_ = fmaxf(sqrtf(fmaf(p0, p0, fmaf(p1, p1, p2 * p2))), MINN_);
    float t = fminf(np_, TCL_);
    float ath = 0.5f * __logf(__fdividef(1.0f + t, 1.0f - t));
    float f = __fdividef(ath, np_);
    o.x = p0 * f; o.y = p1 * f; o.z = p2 * f;
  }
  u0p[idx] = o;
}

// ---------------------------------------------------------------------------
// Shared conv: one thread = one output pixel, all 64 output channels live in
// 16 named v4f registers. Weight addresses are wave-uniform -> scalar loads.
// Fused logmap0(projx(expmap0(t))) == t * min(1, L/||t||).
// ---------------------------------------------------------------------------
__device__ __forceinline__ void conv_clamp(const float4* __restrict__ u0p,
                                           const float* __restrict__ wgt,
                                           const float* __restrict__ bias,
                                           int pix, Acc& a) {
  int b = pix / (H_ * W_);
  int r = pix % (H_ * W_);
  int y = r / W_, x = r % W_;
  const float4* base = u0p + ((size_t)b * HP_ + y) * WP_ + x;
  const v4f* b4 = (const v4f*)bias;
#define INIT(i) a.v##i = b4[i];
  EACH16(INIT)
#undef INIT
#define FMA_X(i) a.v##i += in.x * wp[i];
#define FMA_Y(i) a.v##i += in.y * wp[16 + i];
#define FMA_Z(i) a.v##i += in.z * wp[32 + i];
#define TAP(t) { float4 in = base[((t) / 3) * WP_ + ((t) % 3)];              \
                 const v4f* wp = (const v4f*)(wgt + (t) * 3 * COUT_);        \
                 EACH16(FMA_X) EACH16(FMA_Y) EACH16(FMA_Z) }
  TAP(0) TAP(1) TAP(2) TAP(3) TAP(4) TAP(5) TAP(6) TAP(7) TAP(8)
#undef TAP
#undef FMA_X
#undef FMA_Y
#undef FMA_Z
  v4f s2 = (v4f)0.0f;
#define SQ(i) s2 += a.v##i * a.v##i;
  EACH16(SQ)
#undef SQ
  float n2 = s2.x + s2.y + s2.z + s2.w;
  float n = sqrtf(n2);
  float sc = (n > LCLAMP_) ? (LCLAMP_ / n) : 1.0f;
#define SCL(i) a.v##i *= sc;
  EACH16(SCL)
}

__device__ __forceinline__ v4f vshfl_xor(v4f v, int m) {
  v4f r;
  r.x = __shfl_xor(v.x, m, 64);
  r.y = __shfl_xor(v.y, m, 64);
  r.z = __shfl_xor(v.z, m, 64);
  r.w = __shfl_xor(v.w, m, 64);
  return r;
}

// ---------------------------------------------------------------------------
// K1: THE ONLY conv pass. conv + clamp, then per 32-channel half-pass:
// stage to wave-private LDS, read back transposed (8 b128/thread), and use
// those SAME values twice: (a) coalesced nontemporal store of t to HBM
// (pixel-major, per-instr 8x128B full-sector runs -> no amplification), and
// (b) sum/sumsq accumulation folded over pixel-octets with shfl_xor(8/16/32).
// This removes k3's entire duplicate conv (~100+ us) for +65 us of HBM.
// ---------------------------------------------------------------------------
template <bool STORE_T>
__global__ void __launch_bounds__(256, 4)
k1_stats(const float4* __restrict__ u0p, const float* __restrict__ wgt,
         const float* __restrict__ bias, float* __restrict__ tbuf,
         float* __restrict__ partials) {
  int pix = blockIdx.x * 256 + threadIdx.x;
  Acc a;
  conv_clamp(u0p, wgt, bias, pix, a);

  __shared__ __align__(16) float stg[4 * 64 * PADW2_];  // 36,864 B -> 4 blk/CU
  __shared__ float red_s[256], red_q[256];
  int lane = threadIdx.x & 63, wid = threadIdx.x >> 6;
  float* row = stg + (size_t)(wid * 64 + lane) * PADW2_;
  int pr8 = lane >> 3, qi = lane & 7;
  const float* rb = stg + (size_t)wid * 64 * PADW2_ + pr8 * PADW2_ + qi * 4;
  v4f* outw = (v4f*)tbuf + ((size_t)blockIdx.x * 256 + wid * 64) * 16;

  // ---- pass A: channels 0..31 ----
#define STGA(i) *(v4f*)(row + 4 * (i)) = a.v##i;
  EACH8LO(STGA)
#undef STGA
  __builtin_amdgcn_wave_barrier();
  v4f sA = (v4f)0.0f, qA = (v4f)0.0f;
#pragma unroll
  for (int j = 0; j < 8; j++) {
    v4f v = *(const v4f*)(rb + j * 8 * PADW2_);
    if (STORE_T) __builtin_nontemporal_store(v, outw + (j * 8 + pr8) * 16 + qi);
    sA += v; qA += v * v;
  }
  sA += vshfl_xor(sA, 8);  qA += vshfl_xor(qA, 8);
  sA += vshfl_xor(sA, 16); qA += vshfl_xor(qA, 16);
  sA += vshfl_xor(sA, 32); qA += vshfl_xor(qA, 32);
  if (lane < 8) {  // lane qi holds wave-total for ch quad qi (0..31)
    *(v4f*)&red_s[wid * 32 + qi * 4] = sA;
    *(v4f*)&red_q[wid * 32 + qi * 4] = qA;
  }
  __builtin_amdgcn_wave_barrier();

  // ---- pass B: channels 32..63 (reuse tile; wave DS ops are in-order) ----
#define STGB(i) *(v4f*)(row + 4 * ((i) - 8)) = a.v##i;
  EACH8HI(STGB)
#undef STGB
  __builtin_amdgcn_wave_barrier();
  v4f sB = (v4f)0.0f, qB = (v4f)0.0f;
#pragma unroll
  for (int j = 0; j < 8; j++) {
    v4f v = *(const v4f*)(rb + j * 8 * PADW2_);
    if (STORE_T) __builtin_nontemporal_store(v, outw + (j * 8 + pr8) * 16 + 8 + qi);
    sB += v; qB += v * v;
  }
  sB += vshfl_xor(sB, 8);  qB += vshfl_xor(qB, 8);
  sB += vshfl_xor(sB, 16); qB += vshfl_xor(qB, 16);
  sB += vshfl_xor(sB, 32); qB += vshfl_xor(qB, 32);
  if (lane < 8) {
    *(v4f*)&red_s[128 + wid * 32 + qi * 4] = sB;
    *(v4f*)&red_q[128 + wid * 32 + qi * 4] = qB;
  }
  __syncthreads();
  int tid = threadIdx.x;
  if (tid < 128) {
    int c = tid & 63;
    int base = (c >> 5) * 128 + (c & 31);
    const float* rr = (tid < 64) ? red_s : red_q;
    float tot = rr[base] + rr[base + 32] + rr[base + 64] + rr[base + 96];
    // partials[blk*128 + c] = sum_c ; partials[blk*128 + 64 + c] = sumsq_c
    partials[(size_t)blockIdx.x * 128 + tid] = tot;
  }
}

// ---------------------------------------------------------------------------
// K2: 64 blocks, one per channel. Block c reduces the sum and sumsq columns
// of partials[3136][128] and writes mean[c], rstd*gamma[c].
// ---------------------------------------------------------------------------
__global__ void k2_finalize(const float* __restrict__ partials, const float* __restrict__ gamma,
                            float* __restrict__ stats) {
  int c = blockIdx.x;      // 0..63
  int t = threadIdx.x;     // 256 threads
  float s = 0.f, q = 0.f;
  for (int i = t; i < NBLK_; i += 256) {
    s += partials[(size_t)i * 128 + c];
    q += partials[(size_t)i * 128 + 64 + c];
  }
  __shared__ float ls[256], lq[256];
  ls[t] = s; lq[t] = q;
  __syncthreads();
#pragma unroll
  for (int off = 128; off > 0; off >>= 1) {
    if (t < off) { ls[t] += ls[t + off]; lq[t] += lq[t + off]; }
    __syncthreads();
  }
  if (t == 0) {
    float mean = ls[0] / NF_;
    float msq  = lq[0] / NF_;
    float var = msq - mean * mean;            // jnp.var (ddof=0)
    stats[c] = mean;
    stats[64 + c] = gamma[c] / sqrtf(var + BN_EPS_);
  }
}

// ---------------------------------------------------------------------------
// Shared epilogue: BN affine + clamp + ReLU + expmap0(+projx) on an Acc,
// then two 32-channel wave-private LDS transpose passes -> coalesced stores.
// ---------------------------------------------------------------------------
__device__ __forceinline__ void bn_relu_exp_store(Acc& a, const float* __restrict__ stats,
                                                  const float* __restrict__ beta,
                                                  float* __restrict__ out) {
  const v4f* mean4 = (const v4f*)stats;
  const v4f* rg4   = (const v4f*)(stats + 64);
  const v4f* beta4 = (const v4f*)beta;
  v4f s2 = (v4f)0.0f;
#define BN(i) { a.v##i = (a.v##i - mean4[i]) * rg4[i] + beta4[i]; s2 += a.v##i * a.v##i; }
  EACH16(BN)
#undef BN
  float nv2 = s2.x + s2.y + s2.z + s2.w;
  float nv = sqrtf(nv2);
  float sv = (nv > LCLAMP_) ? (LCLAMP_ / nv) : 1.0f;  // logmap0(expmap0(v)) fused
  v4f z2 = (v4f)0.0f;
#define RELU(i) { v4f r = a.v##i * sv;                                      \
                  r.x = fmaxf(r.x, 0.f); r.y = fmaxf(r.y, 0.f);             \
                  r.z = fmaxf(r.z, 0.f); r.w = fmaxf(r.w, 0.f);             \
                  a.v##i = r; z2 += r * r; }
  EACH16(RELU)
#undef RELU
  float nw2 = z2.x + z2.y + z2.z + z2.w;
  float nw = fmaxf(sqrtf(nw2), MINN_);
  float e2 = __expf(2.0f * nw);                 // tanh via v_exp_f32
  float th = 1.0f - __fdividef(2.0f, e2 + 1.0f);
  float se = __fdividef(th, nw);
  float clip = fminf(1.0f, MAXNORM_ / fmaxf(th, MINN_));
  float fs = se * clip;

  __shared__ __align__(16) float stg[4 * 64 * PADW2_];  // 36,864 B -> 4 blk/CU
  int lane = threadIdx.x & 63, wid = threadIdx.x >> 6;
  float* row = stg + (size_t)(wid * 64 + lane) * PADW2_;
  int pr8 = lane >> 3, qi = lane & 7;
  const float* rb = stg + (size_t)wid * 64 * PADW2_ + pr8 * PADW2_ + qi * 4;
  v4f* outw = (v4f*)out + ((size_t)blockIdx.x * 256 + wid * 64) * 16;

#define STGA(i) *(v4f*)(row + 4 * (i)) = a.v##i * fs;
  EACH8LO(STGA)
#undef STGA
  __builtin_amdgcn_wave_barrier();
#pragma unroll
  for (int j = 0; j < 8; j++) {
    v4f v = *(const v4f*)(rb + j * 8 * PADW2_);
    __builtin_nontemporal_store(v, outw + (j * 8 + pr8) * 16 + qi);
  }
  __builtin_amdgcn_wave_barrier();
#define STGB(i) *(v4f*)(row + 4 * ((i) - 8)) = a.v##i * fs;
  EACH8HI(STGB)
#undef STGB
  __builtin_amdgcn_wave_barrier();
#pragma unroll
  for (int j = 0; j < 8; j++) {
    v4f v = *(const v4f*)(rb + j * 8 * PADW2_);
    __builtin_nontemporal_store(v, outw + (j * 8 + pr8) * 16 + 8 + qi);
  }
}

// ---------------------------------------------------------------------------
// K3 (fast path): NO conv. Stream t back (16 b128/thread at 256B stride --
// the wave's 16KB span lives in L1 across the 16 loads, so FETCH stays at
// ~205MB), apply the epilogue, transpose-store. Pure memory op: ~70us floor.
// ---------------------------------------------------------------------------
__global__ void __launch_bounds__(256, 4)
k3_from_t(const float* __restrict__ tbuf, const float* __restrict__ stats,
          const float* __restrict__ beta, float* __restrict__ out) {
  int pix = blockIdx.x * 256 + threadIdx.x;
  const v4f* tp = (const v4f*)tbuf + (size_t)pix * 16;
  Acc a;
#define LOADT(i) a.v##i = tp[i];
  EACH16(LOADT)
#undef LOADT
  bn_relu_exp_store(a, stats, beta, out);
}

// K3 (fallback when ws can't hold t): recompute conv as before.
__global__ void __launch_bounds__(256, 4)
k3_fused(const float4* __restrict__ u0p, const float* __restrict__ wgt,
         const float* __restrict__ bias, const float* __restrict__ stats,
         const float* __restrict__ beta, float* __restrict__ out) {
  int pix = blockIdx.x * 256 + threadIdx.x;
  Acc a;
  conv_clamp(u0p, wgt, bias, pix, a);
  bn_relu_exp_store(a, stats, beta, out);
}

// ---------------------------------------------------------------------------
extern "C" void kernel_launch(void* const* d_in, const int* in_sizes, int n_in,
                              void* d_out, int out_size, void* d_ws, size_t ws_size,
                              hipStream_t stream) {
  const float* x     = (const float*)d_in[0];  // [16,3,224,224]
  const float* wgt   = (const float*)d_in[1];  // [3,3,3,64] HWIO
  const float* bias  = (const float*)d_in[2];  // [64]
  const float* gamma = (const float*)d_in[3];  // [64]
  const float* beta  = (const float*)d_in[4];  // [64]
  float* out = (float*)d_out;                  // [16,224,224,64]

  char* ws = (char*)d_ws;
  float4* u0p      = (float4*)ws;                                           // 13,075,456 B
  float*  partials = (float*)(ws + (size_t)NPAD_ * 16);                     //  1,605,632 B
  float*  stats    = (float*)(ws + (size_t)NPAD_ * 16 + (size_t)NBLK_ * 128 * 4); // 512 B
  size_t  t_off    = (size_t)NPAD_ * 16 + (size_t)NBLK_ * 128 * 4 + 512;    // 16B-aligned
  float*  tbuf     = (float*)(ws + t_off);                                  // 205,520,896 B
  bool have_t = ws_size >= t_off + (size_t)NPIX_ * COUT_ * 4;

  hipLaunchKernelGGL(k0_transform, dim3((NPAD_ + 255) / 256), dim3(256), 0, stream, x, u0p);
  if (have_t) {
    hipLaunchKernelGGL((k1_stats<true>),  dim3(NBLK_), dim3(256), 0, stream, u0p, wgt, bias, tbuf, partials);
    hipLaunchKernelGGL(k2_finalize,       dim3(64),    dim3(256), 0, stream, partials, gamma, stats);
    hipLaunchKernelGGL(k3_from_t,         dim3(NBLK_), dim3(256), 0, stream, tbuf, stats, beta, out);
  } else {
    hipLaunchKernelGGL((k1_stats<false>), dim3(NBLK_), dim3(256), 0, stream, u0p, wgt, bias, tbuf, partials);
    hipLaunchKernelGGL(k2_finalize,       dim3(64),    dim3(256), 0, stream, partials, gamma, stats);
    hipLaunchKernelGGL(k3_fused,          dim3(NBLK_), dim3(256), 0, stream, u0p, wgt, bias, stats, beta, out);
  }
}

// Round 4
// 311.091 us; speedup vs baseline: 1.1764x; 1.1764x over previous
//
#include <hip/hip_runtime.h>
#include <math.h>

#define B_ 16
#define H_ 224
#define W_ 224
#define HP_ 226
#define WP_ 226
#define CIN_ 3
#define COUT_ 64
#define NPIX_ (B_ * H_ * W_)      /* 802816 */
#define NPAD_ (B_ * HP_ * WP_)    /* 817216 */
#define NBLK_ (NPIX_ / 256)       /* 3136 */
#define MAXNORM_ 0.999f
#define MINN_ 1e-7f
#define TCL_ (1.0f - 1e-5f)
#define LCLAMP_ 3.8002012f        /* atanh(0.999) */
#define BN_EPS_ 1e-5f
#define NF_ ((float)NPIX_)
/* Half-tile LDS row stride (floats): 32 ch + 4 pad = 36 = 9 quads (odd).
   b128 write: lane start-bank (36*lane)%32 -> 2x per 4-bank group = floor.
   b128 transposed read (rb): 8 distinct groups per 8-lane phase = floor. */
#define PADW2_ 36

typedef float v4f __attribute__((ext_vector_type(4)));

// 32 accumulators as 8 NAMED vector members (macro-expanded constant names ->
// SSA values, immune to the SROA alloca trap). Half-conv design: peak live
// regs ~90 -> fits the 128-VGPR cap of __launch_bounds__(256,4) with NO
// scratch spill. R2's full-64ch Acc needed ~200 live under a 128 cap ->
// silent scratch spills (L2-resident, invisible in FETCH/WRITE, fatal for
// latency). R3 proved the other sin: 256B-lane-stride reads cap at 2.3 TB/s
// (outstanding-miss budget), so every global access here is per-instruction
// contiguous.
struct Acc8 {
  v4f v0, v1, v2, v3, v4, v5, v6, v7;
};

#define EACH8(X) X(0) X(1) X(2) X(3) X(4) X(5) X(6) X(7)

// ---------------------------------------------------------------------------
// K0: x (NCHW f32) -> u0p (padded NHWC4): u0 = logmap0(projx(x)) per pixel,
// zero halo ring. atanh(t) = 0.5*log((1+t)/(1-t)) via v_log_f32.
// ---------------------------------------------------------------------------
__global__ void k0_transform(const float* __restrict__ x, float4* __restrict__ u0p) {
  int idx = blockIdx.x * 256 + threadIdx.x;
  if (idx >= NPAD_) return;
  int b = idx / (HP_ * WP_);
  int r = idx % (HP_ * WP_);
  int yp = r / WP_, xp = r % WP_;
  float4 o = make_float4(0.f, 0.f, 0.f, 0.f);
  if (yp >= 1 && yp <= H_ && xp >= 1 && xp <= W_) {
    const float* xb = x + (size_t)b * (CIN_ * H_ * W_) + (size_t)(yp - 1) * W_ + (xp - 1);
    float v0 = xb[0];
    float v1 = xb[H_ * W_];
    float v2 = xb[2 * H_ * W_];
    // projx
    float n = sqrtf(fmaf(v0, v0, fmaf(v1, v1, v2 * v2)));
    float ncl = fmaxf(n, MINN_);
    float s = fminf(1.0f, MAXNORM_ / ncl);
    float p0 = v0 * s, p1 = v1 * s, p2 = v2 * s;
    // logmap0
    float np_ = fmaxf(sqrtf(fmaf(p0, p0, fmaf(p1, p1, p2 * p2))), MINN_);
    float t = fminf(np_, TCL_);
    float ath = 0.5f * __logf(__fdividef(1.0f + t, 1.0f - t));
    float f = __fdividef(ath, np_);
    o.x = p0 * f; o.y = p1 * f; o.z = p2 * f;
  }
  u0p[idx] = o;
}

// ---------------------------------------------------------------------------
// Half-conv: output channels [32h, 32h+32) for one pixel into 8 named v4f.
// Tap loads are per-instruction contiguous (16B x 64 consecutive lanes);
// weight addresses wave-uniform. Running the conv twice per kernel doubles
// tap loads only (L1-hot, ~12KB/block working set) -- FMA count unchanged.
// ---------------------------------------------------------------------------
__device__ __forceinline__ void conv_half(const float4* __restrict__ u0p,
                                          const float* __restrict__ wgt,
                                          const float* __restrict__ bias,
                                          int pix, int h, Acc8& a) {
  int b = pix / (H_ * W_);
  int r = pix % (H_ * W_);
  int y = r / W_, x = r % W_;
  const float4* base = u0p + ((size_t)b * HP_ + y) * WP_ + x;
  const v4f* b4 = (const v4f*)bias;
  int h8 = h * 8;
#define INIT(i) a.v##i = b4[h8 + i];
  EACH8(INIT)
#undef INIT
#define FMA_X(i) a.v##i += in.x * wp[h8 + i];
#define FMA_Y(i) a.v##i += in.y * wp[16 + h8 + i];
#define FMA_Z(i) a.v##i += in.z * wp[32 + h8 + i];
#define TAP(t) { float4 in = base[((t) / 3) * WP_ + ((t) % 3)];              \
                 const v4f* wp = (const v4f*)(wgt + (t) * 3 * COUT_);        \
                 EACH8(FMA_X) EACH8(FMA_Y) EACH8(FMA_Z) }
  TAP(0) TAP(1) TAP(2) TAP(3) TAP(4) TAP(5) TAP(6) TAP(7) TAP(8)
#undef TAP
#undef FMA_X
#undef FMA_Y
#undef FMA_Z
}

__device__ __forceinline__ v4f vshfl_xor(v4f v, int m) {
  v4f r;
  r.x = __shfl_xor(v.x, m, 64);
  r.y = __shfl_xor(v.y, m, 64);
  r.z = __shfl_xor(v.z, m, 64);
  r.w = __shfl_xor(v.w, m, 64);
  return r;
}
__device__ __forceinline__ v4f vrelu(v4f v) {
  v.x = fmaxf(v.x, 0.f); v.y = fmaxf(v.y, 0.f);
  v.z = fmaxf(v.z, 0.f); v.w = fmaxf(v.w, 0.f);
  return v;
}
__device__ __forceinline__ float hsum(v4f v) { return (v.x + v.y) + (v.z + v.w); }

// ---------------------------------------------------------------------------
// K1: conv (two 32-ch halves) + DEFERRED clamp + stats. The clamp scale
// sc = min(1, L/||t||) needs all 64 channels, so: stage raw half-A to the
// wave-private LDS tile, run half-B (keeping it in regs), compute sc from
// s2A+s2B, publish sc[pixel] to LDS, then do the transposed stat read-back
// applying sc[row] on the fly (8-lane broadcast reads, conflict-free).
// Half-B is then staged and reduced the same way. Register-light ->真 4 blk/CU.
// ---------------------------------------------------------------------------
__global__ void __launch_bounds__(256, 4)
k1_stats(const float4* __restrict__ u0p, const float* __restrict__ wgt,
         const float* __restrict__ bias, float* __restrict__ partials) {
  int pix = blockIdx.x * 256 + threadIdx.x;
  __shared__ __align__(16) float stg[4 * 64 * PADW2_];  // 36,864 B
  __shared__ float scl[256];                            // per-pixel clamp scale
  __shared__ float red_s[256], red_q[256];
  int lane = threadIdx.x & 63, wid = threadIdx.x >> 6;
  float* row = stg + (size_t)(wid * 64 + lane) * PADW2_;
  int pr8 = lane >> 3, qi = lane & 7;
  const float* rb = stg + (size_t)wid * 64 * PADW2_ + pr8 * PADW2_ + qi * 4;
  const float* scrow = scl + wid * 64;

  Acc8 a;
  conv_half(u0p, wgt, bias, pix, 0, a);
  v4f s2v = (v4f)0.0f;
#define SQ(i) s2v += a.v##i * a.v##i;
  EACH8(SQ)
#undef SQ
  float s2A = hsum(s2v);
  // stage raw half-A
#define STG(i) *(v4f*)(row + 4 * (i)) = a.v##i;
  EACH8(STG)
#undef STG
  __builtin_amdgcn_wave_barrier();

  conv_half(u0p, wgt, bias, pix, 1, a);   // half-B lives in regs
  s2v = (v4f)0.0f;
#define SQ(i) s2v += a.v##i * a.v##i;
  EACH8(SQ)
#undef SQ
  float n2 = s2A + hsum(s2v);
  float n = sqrtf(n2);
  float sc = (n > LCLAMP_) ? (LCLAMP_ / n) : 1.0f;
  scl[wid * 64 + lane] = sc;
  __builtin_amdgcn_wave_barrier();

  // transposed stat read of half-A, applying sc[row]
  v4f sA = (v4f)0.0f, qA = (v4f)0.0f;
#pragma unroll
  for (int j = 0; j < 8; j++) {
    float g = scrow[j * 8 + pr8];
    v4f v = *(const v4f*)(rb + j * 8 * PADW2_) * g;
    sA += v; qA += v * v;
  }
  sA += vshfl_xor(sA, 8);  qA += vshfl_xor(qA, 8);
  sA += vshfl_xor(sA, 16); qA += vshfl_xor(qA, 16);
  sA += vshfl_xor(sA, 32); qA += vshfl_xor(qA, 32);
  if (lane < 8) {  // lane qi holds wave-total for ch quad qi (ch 0..31)
    *(v4f*)&red_s[wid * 32 + qi * 4] = sA;
    *(v4f*)&red_q[wid * 32 + qi * 4] = qA;
  }
  __builtin_amdgcn_wave_barrier();

  // stage half-B (wave DS ops in order: A-reads above complete first)
#define STG(i) *(v4f*)(row + 4 * (i)) = a.v##i;
  EACH8(STG)
#undef STG
  __builtin_amdgcn_wave_barrier();
  v4f sB = (v4f)0.0f, qB = (v4f)0.0f;
#pragma unroll
  for (int j = 0; j < 8; j++) {
    float g = scrow[j * 8 + pr8];
    v4f v = *(const v4f*)(rb + j * 8 * PADW2_) * g;
    sB += v; qB += v * v;
  }
  sB += vshfl_xor(sB, 8);  qB += vshfl_xor(qB, 8);
  sB += vshfl_xor(sB, 16); qB += vshfl_xor(qB, 16);
  sB += vshfl_xor(sB, 32); qB += vshfl_xor(qB, 32);
  if (lane < 8) {
    *(v4f*)&red_s[128 + wid * 32 + qi * 4] = sB;
    *(v4f*)&red_q[128 + wid * 32 + qi * 4] = qB;
  }
  __syncthreads();
  int tid = threadIdx.x;
  if (tid < 128) {
    int c = tid & 63;
    int base = (c >> 5) * 128 + (c & 31);
    const float* rr = (tid < 64) ? red_s : red_q;
    float tot = rr[base] + rr[base + 32] + rr[base + 64] + rr[base + 96];
    // partials[blk*128 + c] = sum_c ; partials[blk*128 + 64 + c] = sumsq_c
    partials[(size_t)blockIdx.x * 128 + tid] = tot;
  }
}

// ---------------------------------------------------------------------------
// K2: 64 blocks, one per channel. Block c reduces the sum and sumsq columns
// of partials[3136][128] and writes mean[c], rstd*gamma[c].
// ---------------------------------------------------------------------------
__global__ void k2_finalize(const float* __restrict__ partials, const float* __restrict__ gamma,
                            float* __restrict__ stats) {
  int c = blockIdx.x;      // 0..63
  int t = threadIdx.x;     // 256 threads
  float s = 0.f, q = 0.f;
  for (int i = t; i < NBLK_; i += 256) {
    s += partials[(size_t)i * 128 + c];
    q += partials[(size_t)i * 128 + 64 + c];
  }
  __shared__ float ls[256], lq[256];
  ls[t] = s; lq[t] = q;
  __syncthreads();
#pragma unroll
  for (int off = 128; off > 0; off >>= 1) {
    if (t < off) { ls[t] += ls[t + off]; lq[t] += lq[t + off]; }
    __syncthreads();
  }
  if (t == 0) {
    float mean = ls[0] / NF_;
    float msq  = lq[0] / NF_;
    float var = msq - mean * mean;            // jnp.var (ddof=0)
    stats[c] = mean;
    stats[64 + c] = gamma[c] / sqrtf(var + BN_EPS_);
  }
}

// ---------------------------------------------------------------------------
// K3: conv (two halves) + BN affine, with the ENTIRE nonlinear tail folded
// into one per-pixel scalar: since sv>0, relu(sv*u) = sv*relu(u), so
//   out = fs * relu(sv*u) = g * relu(u),  g = fs*sv,
// where nv2 = sum u^2 (-> sv) and r2 = sum relu(u)^2 (-> nw = sv*sqrt(r2)
// -> fs) are accumulated in registers across both halves. Stage raw BN'd u,
// publish g[pixel], then transposed read applies relu + g[row] and stores
// coalesced (8 x 128B full-sector runs per instruction). tanh via v_exp.
// ---------------------------------------------------------------------------
__global__ void __launch_bounds__(256, 4)
k3_final(const float4* __restrict__ u0p, const float* __restrict__ wgt,
         const float* __restrict__ bias, const float* __restrict__ stats,
         const float* __restrict__ beta, float* __restrict__ out) {
  int pix = blockIdx.x * 256 + threadIdx.x;
  __shared__ __align__(16) float stg[4 * 64 * PADW2_];  // 36,864 B
  __shared__ float gl[256];                             // per-pixel out scale
  int lane = threadIdx.x & 63, wid = threadIdx.x >> 6;
  float* row = stg + (size_t)(wid * 64 + lane) * PADW2_;
  int pr8 = lane >> 3, qi = lane & 7;
  const float* rb = stg + (size_t)wid * 64 * PADW2_ + pr8 * PADW2_ + qi * 4;
  const float* grow = gl + wid * 64;
  v4f* outw = (v4f*)out + ((size_t)blockIdx.x * 256 + wid * 64) * 16;

  const v4f* mean4 = (const v4f*)stats;
  const v4f* rg4   = (const v4f*)(stats + 64);
  const v4f* beta4 = (const v4f*)beta;

  Acc8 a;
  // ---- half A: conv + BN, accumulate nv2 (pre-relu) and r2 (post-relu) ----
  conv_half(u0p, wgt, bias, pix, 0, a);
  v4f s2v = (v4f)0.0f, r2v = (v4f)0.0f;
#define BNA(i) { a.v##i = (a.v##i - mean4[i]) * rg4[i] + beta4[i];           \
                 s2v += a.v##i * a.v##i; v4f t_ = vrelu(a.v##i); r2v += t_ * t_; }
  EACH8(BNA)
#undef BNA
  float nv2 = hsum(s2v), r2 = hsum(r2v);
  // stage raw BN'd half-A
#define STG(i) *(v4f*)(row + 4 * (i)) = a.v##i;
  EACH8(STG)
#undef STG
  __builtin_amdgcn_wave_barrier();

  // ---- half B: conv + BN (stats quads 8..15), finish scalars ----
  conv_half(u0p, wgt, bias, pix, 1, a);
  s2v = (v4f)0.0f; r2v = (v4f)0.0f;
#define BNB(i) { a.v##i = (a.v##i - mean4[8 + i]) * rg4[8 + i] + beta4[8 + i]; \
                 s2v += a.v##i * a.v##i; v4f t_ = vrelu(a.v##i); r2v += t_ * t_; }
  EACH8(BNB)
#undef BNB
  nv2 += hsum(s2v); r2 += hsum(r2v);
  float nv = sqrtf(nv2);
  float sv = (nv > LCLAMP_) ? (LCLAMP_ / nv) : 1.0f;  // logmap0(expmap0(v)) fused
  float nw = fmaxf(sv * sqrtf(r2), MINN_);
  float e2 = __expf(2.0f * nw);                        // tanh via v_exp_f32
  float th = 1.0f - __fdividef(2.0f, e2 + 1.0f);
  float se = __fdividef(th, nw);
  float clip = fminf(1.0f, MAXNORM_ / fmaxf(th, MINN_));
  float g = se * clip * sv;
  gl[wid * 64 + lane] = g;
  __builtin_amdgcn_wave_barrier();

  // ---- store half A: transposed read, relu + g[row], coalesced NT store ----
#pragma unroll
  for (int j = 0; j < 8; j++) {
    float gv = grow[j * 8 + pr8];
    v4f v = vrelu(*(const v4f*)(rb + j * 8 * PADW2_)) * gv;
    __builtin_nontemporal_store(v, outw + (j * 8 + pr8) * 16 + qi);
  }
  __builtin_amdgcn_wave_barrier();

  // ---- stage + store half B (quads 8..15 of each pixel) ----
#define STG(i) *(v4f*)(row + 4 * (i)) = a.v##i;
  EACH8(STG)
#undef STG
  __builtin_amdgcn_wave_barrier();
#pragma unroll
  for (int j = 0; j < 8; j++) {
    float gv = grow[j * 8 + pr8];
    v4f v = vrelu(*(const v4f*)(rb + j * 8 * PADW2_)) * gv;
    __builtin_nontemporal_store(v, outw + (j * 8 + pr8) * 16 + 8 + qi);
  }
}

// ---------------------------------------------------------------------------
extern "C" void kernel_launch(void* const* d_in, const int* in_sizes, int n_in,
                              void* d_out, int out_size, void* d_ws, size_t ws_size,
                              hipStream_t stream) {
  const float* x     = (const float*)d_in[0];  // [16,3,224,224]
  const float* wgt   = (const float*)d_in[1];  // [3,3,3,64] HWIO
  const float* bias  = (const float*)d_in[2];  // [64]
  const float* gamma = (const float*)d_in[3];  // [64]
  const float* beta  = (const float*)d_in[4];  // [64]
  float* out = (float*)d_out;                  // [16,224,224,64]

  char* ws = (char*)d_ws;
  float4* u0p      = (float4*)ws;                                           // 13,075,456 B
  float*  partials = (float*)(ws + (size_t)NPAD_ * 16);                     //  1,605,632 B
  float*  stats    = (float*)(ws + (size_t)NPAD_ * 16 + (size_t)NBLK_ * 128 * 4); // 512 B

  hipLaunchKernelGGL(k0_transform, dim3((NPAD_ + 255) / 256), dim3(256), 0, stream, x, u0p);
  hipLaunchKernelGGL(k1_stats,     dim3(NBLK_),               dim3(256), 0, stream, u0p, wgt, bias, partials);
  hipLaunchKernelGGL(k2_finalize,  dim3(64),                  dim3(256), 0, stream, partials, gamma, stats);
  hipLaunchKernelGGL(k3_final,     dim3(NBLK_),               dim3(256), 0, stream, u0p, wgt, bias, stats, beta, out);
}